// Round 2
// 3983.986 us; speedup vs baseline: 1.0849x; 1.0849x over previous
//
#include <hip/hip_runtime.h>
#include <stdint.h>

#define IN    64
#define H     1024
#define G4    4096      // 4*H gate rows
#define BATCH 128
#define SEQ   256
#define TLEN  96
#define KCAT  1088      // IN + H
#define NSTEP (SEQ + TLEN)
#define NBLK  256
#define HPAD  1032      // h row stride in LDS (bf16), +8 pad

typedef __attribute__((ext_vector_type(8))) short bf16x8;
typedef __attribute__((ext_vector_type(4))) float f32x4;

__device__ __forceinline__ unsigned short f2bf(float f) {
  union { float f; uint32_t u; } v; v.f = f;
  uint32_t u = v.u;
  return (unsigned short)((u + 0x7fffu + ((u >> 16) & 1u)) >> 16);  // RNE
}

// global->LDS direct copy, 16B/lane, aux=1 (SC0: bypass L1 so same-XCD L2 dirty
// lines from other CUs are observed). LDS dest = wave-uniform base + lane*16.
__device__ __forceinline__ void gload_lds16_sc0(const unsigned short* g, unsigned short* l) {
  __builtin_amdgcn_global_load_lds((const __attribute__((address_space(1))) unsigned int*)g,
                                   (__attribute__((address_space(3))) unsigned int*)l, 16, 0, 1);
}

// ---------- generic fp32 -> bf16 ----------
__global__ void k_convert(const float* __restrict__ src, unsigned short* __restrict__ dst, int n) {
  int i = blockIdx.x * blockDim.x + threadIdx.x;
  int stride = gridDim.x * blockDim.x;
  for (; i < n; i += stride) dst[i] = f2bf(src[i]);
}

// ---------- pack [Wih | Whh] gate-interleaved: packed row p=4j+g <-> torch row r=g*H+j ----------
__global__ void k_pack(const float* __restrict__ Wih, const float* __restrict__ Whh,
                       const float* __restrict__ bih, const float* __restrict__ bhh,
                       unsigned short* __restrict__ Wcat, float* __restrict__ bcat) {
  int p = blockIdx.x;                    // 0..4095
  int j = p >> 2, g = p & 3;
  int r = g * H + j;
  for (int c = threadIdx.x; c < KCAT; c += blockDim.x) {
    float v = (c < IN) ? Wih[r * IN + c] : Whh[r * H + (c - IN)];
    Wcat[(size_t)p * KCAT + c] = f2bf(v);
  }
  if (threadIdx.x == 0) bcat[p] = bih[r] + bhh[r];
}

// ---------- decoder fused weights: W_eff = Whh + Wih@lin ; b_eff = bih+bhh+Wih@lin_b ----------
__global__ void k_deceff(const float* __restrict__ Wih, const float* __restrict__ Whh,
                         const float* __restrict__ bih, const float* __restrict__ bhh,
                         const float* __restrict__ lin, const float* __restrict__ linb,
                         unsigned short* __restrict__ Weff, float* __restrict__ beff) {
  int p = blockIdx.x;
  int j = p >> 2, g = p & 3;
  int r = g * H + j;
  __shared__ float wr[IN];
  if (threadIdx.x < IN) wr[threadIdx.x] = Wih[r * IN + threadIdx.x];
  __syncthreads();
  for (int k = threadIdx.x; k < H; k += blockDim.x) {
    float acc = Whh[(size_t)r * H + k];
    #pragma unroll 8
    for (int i = 0; i < IN; ++i) acc += wr[i] * lin[(size_t)i * H + k];
    Weff[(size_t)p * H + k] = f2bf(acc);
  }
  if (threadIdx.x == 0) {
    float s = bih[r] + bhh[r];
    for (int i = 0; i < IN; ++i) s += wr[i] * linb[i];
    beff[p] = s;
  }
}

// ---------- persistent LSTM: XCD-local groups, weights in registers ----------
// Deltas vs the 4322us passing baseline (ONE risky subsystem at a time --
// the inter-block flag barrier is byte-for-byte the proven primitive):
//  (1) operand-swapped MFMA (compute z^T = W*h): A = W-frag, B = h-frag. Both
//      fragment layouts index (lane&15, (lane>>4)*8+j), so the existing
//      register/LDS data feeds either slot unchanged. The D layout then gives
//      each lane the full i,f,g,o gate quad of one
//      (batch row = lane&15, unit = slot*32+wave*4+(lane>>4)): the LSTM cell
//      is lane-local -- no z scatter to LDS, no zs re-read, no per-step global
//      bias loads (bias lives in 4 registers, reloaded at t=0/SEQ/SEQ+1 only).
//      A tiny 2-byte LDS transpose keeps the coalesced 64B-per-row h store.
//  (2) dual accumulators halve the dependent-MFMA chain (only 2 waves/SIMD).
// NOTE: dynamic-LDS request stays 86016 B on purpose: >80KB clamps occupancy
// to 1 block/CU, which pigeonholes exactly 32 blocks per XCD -- the ticket
// barrier REQUIRES that distribution (33/31 split would deadlock).
__global__ __launch_bounds__(512, 2) void k_lstm(
    const unsigned short* __restrict__ xin,
    const unsigned short* __restrict__ Wenc,  const float* __restrict__ benc,
    const unsigned short* __restrict__ Wdec0, const float* __restrict__ bdec0,
    const unsigned short* __restrict__ Wdeff, const float* __restrict__ bdeff,
    unsigned short* __restrict__ hbuf, unsigned short* __restrict__ hhist,
    unsigned int* __restrict__ flags, unsigned int* __restrict__ tickets)
{
  extern __shared__ char smem[];
  unsigned short* hs = (unsigned short*)smem;              // 16 x HPAD bf16 = 33024 B
  __shared__ unsigned short ht[16][40];                    // h transpose staging (+pad)
  __shared__ int s_xcd, s_slot;
  const int tid  = threadIdx.x;
  const int lane = tid & 63;
  const int wave = tid >> 6;             // 0..7
  if (tid == 0) {
    unsigned x;
    asm volatile("s_getreg_b32 %0, hwreg(HW_REG_XCC_ID)" : "=s"(x));
    x &= 7;
    unsigned tk = __hip_atomic_fetch_add(&tickets[x], 1u, __ATOMIC_RELAXED, __HIP_MEMORY_SCOPE_AGENT);
    s_xcd = (int)x; s_slot = (int)(tk & 31);
  }
  __syncthreads();
  const int grp  = s_xcd;                // row-group == physical XCD
  const int slot = s_slot;               // col slot 0..31
  const int m0   = grp * 16;             // batch rows
  const int n0   = slot * 128;           // packed gate cols (unused directly now)
  const int gw   = n0 + wave * 16;       // this wave's 16 packed gate rows
  const int fm   = lane & 15;            // frag non-K index (batch row / gate row)
  const int fku  = lane >> 4;            // 0..3
  const int fk   = fku * 8;              // frag K offset
  const int unit = slot * 32 + wave * 4 + fku;   // h-unit this lane owns (0..1023)
  const int hrow = tid >> 5;             // store phase: batch row 0..15
  const int hcol = tid & 31;             // store phase: unit-local col 0..31
  const unsigned int* myflags = flags + (size_t)grp * 32;   // packed: 32 x 4B = 128 B

  bf16x8 B[34];                          // [0..31] h-part K-tiles, [32..33] x-part
  float4 bias4;
  float cst = 0.f;
  int p = 0;
  for (int t = 0; t < NSTEP; ++t) {
    const bool is_enc = (t < SEQ);
    // ---- rare uniform weight (re)loads into registers ----
    if (t == 0 || t == SEQ) {
      const unsigned short* W = (t == 0) ? Wenc : Wdec0;
      const unsigned short* wr = W + (size_t)(gw + fm) * KCAT + fk;
      #pragma unroll
      for (int kt = 0; kt < 32; ++kt) B[kt] = *(const bf16x8*)(wr + IN + kt * 32);
      B[32] = *(const bf16x8*)(wr);
      B[33] = *(const bf16x8*)(wr + 32);
    } else if (t == SEQ + 1) {
      const unsigned short* wr = Wdeff + (size_t)(gw + fm) * H + fk;
      #pragma unroll
      for (int kt = 0; kt < 32; ++kt) B[kt] = *(const bf16x8*)(wr + kt * 32);
    }
    if (t == 0 || t == SEQ || t == SEQ + 1) {
      const float* bptr = (t == 0) ? benc : (t == SEQ ? bdec0 : bdeff);
      bias4 = *(const float4*)&bptr[4 * unit];   // i,f,g,o biases of this lane's unit
    }
    const unsigned short* xsrc =
        is_enc ? xin + (size_t)t * BATCH * IN
               : (t == SEQ ? xin + (size_t)(SEQ - 1) * BATCH * IN : nullptr);
    // ---- stage h(t) rows (16 x 1024 bf16 = 32 KB) from XCD L2 into LDS ----
    if (t > 0) {
      const unsigned short* hb = hbuf + (size_t)p * BATCH * H + (size_t)m0 * H;
      #pragma unroll
      for (int j = 0; j < 4; ++j) {
        int row  = wave * 2 + (j >> 1);
        int half = (j & 1) * 512;
        gload_lds16_sc0(hb + (size_t)row * H + half + lane * 8, &hs[row * HPAD + half]);
      }
    }
    __syncthreads();   // staging complete (vmcnt drained before s_barrier)
    // ---- K-loop, operand-swapped: D = W(A) * h(B) = z^T, two acc chains ----
    f32x4 acc0 = {0.f, 0.f, 0.f, 0.f};
    f32x4 acc1 = {0.f, 0.f, 0.f, 0.f};
    if (t > 0) {
      const unsigned short* as = &hs[fm * HPAD + fk];
      #pragma unroll
      for (int kt = 0; kt < 32; kt += 2) {
        acc0 = __builtin_amdgcn_mfma_f32_16x16x32_bf16(B[kt],     *(const bf16x8*)(as + kt * 32),      acc0, 0, 0, 0);
        acc1 = __builtin_amdgcn_mfma_f32_16x16x32_bf16(B[kt + 1], *(const bf16x8*)(as + kt * 32 + 32), acc1, 0, 0, 0);
      }
    }
    if (xsrc) {
      const unsigned short* xa = xsrc + (size_t)(m0 + fm) * IN + fk;
      acc0 = __builtin_amdgcn_mfma_f32_16x16x32_bf16(B[32], *(const bf16x8*)(xa),      acc0, 0, 0, 0);
      acc1 = __builtin_amdgcn_mfma_f32_16x16x32_bf16(B[33], *(const bf16x8*)(xa + 32), acc1, 0, 0, 0);
    }
    // ---- fused LSTM cell, fully lane-local: D row = 4*unit_local + gate, col = batch row ----
    {
      float zi = acc0[0] + acc1[0] + bias4.x;
      float zf = acc0[1] + acc1[1] + bias4.y;
      float zg = acc0[2] + acc1[2] + bias4.z;
      float zo = acc0[3] + acc1[3] + bias4.w;
      float gi = 1.f / (1.f + __expf(-zi));
      float gf = 1.f / (1.f + __expf(-zf));
      float gg = tanhf(zg);
      float go = 1.f / (1.f + __expf(-zo));
      float c  = gf * cst + gi * gg;
      cst = c;
      float h = go * tanhf(c);
      ht[fm][(wave << 2) + fku] = f2bf(h);   // tiny LDS transpose for coalesced store
    }
    __syncthreads();
    // ---- coalesced global h store: 32 consecutive tids write one 64B line ----
    {
      unsigned short hv = ht[hrow][hcol];
      size_t idx = (size_t)(m0 + hrow) * H + (size_t)slot * 32 + hcol;
      hbuf[(size_t)(1 - p) * BATCH * H + idx] = hv;            // plain store -> XCD L2
      if (!is_enc) hhist[(size_t)(t - SEQ) * BATCH * H + idx] = hv;
    }
    p ^= 1;
    // ---- XCD-local epoch barrier over 32 blocks (PROVEN primitive, unchanged) ----
    if (t + 1 < NSTEP) {
      __syncthreads();   // drains all waves' h stores into L2 before flag
      if (tid == 0)
        __hip_atomic_store(&flags[grp * 32 + slot], (unsigned)(t + 1),
                           __ATOMIC_RELAXED, __HIP_MEMORY_SCOPE_AGENT);
      if (tid < 32) {
        while (__hip_atomic_load(&myflags[tid], __ATOMIC_RELAXED, __HIP_MEMORY_SCOPE_AGENT) < (unsigned)(t + 1))
          __builtin_amdgcn_s_sleep(1);
      }
      __syncthreads();
    }
  }
}

// ---------- epilogue: all 96 outputs in one GEMM  y = hhist @ lin^T + lin_b ----------
__global__ __launch_bounds__(256) void k_out(
    const unsigned short* __restrict__ hhist, const unsigned short* __restrict__ linb16,
    const float* __restrict__ linb, float* __restrict__ out)
{
  const int tid  = threadIdx.x;
  const int lane = tid & 63;
  const int wave = tid >> 6;
  const int fm   = lane & 15;
  const int fk   = (lane >> 4) * 8;
  const int R0   = blockIdx.x * 64 + wave * 16;
  f32x4 acc[4] = {{0.f,0.f,0.f,0.f},{0.f,0.f,0.f,0.f},{0.f,0.f,0.f,0.f},{0.f,0.f,0.f,0.f}};
  const unsigned short* ha = hhist + (size_t)(R0 + fm) * H + fk;
  #pragma unroll 2
  for (int kc = 0; kc < H; kc += 32) {
    bf16x8 a = *(const bf16x8*)(ha + kc);
    #pragma unroll
    for (int nq = 0; nq < 4; ++nq) {
      bf16x8 b = *(const bf16x8*)(linb16 + (size_t)(nq * 16 + fm) * H + fk + kc);
      acc[nq] = __builtin_amdgcn_mfma_f32_16x16x32_bf16(a, b, acc[nq], 0, 0, 0);
    }
  }
  #pragma unroll
  for (int nq = 0; nq < 4; ++nq) {
    int col = nq * 16 + fm;
    float bb = linb[col];
    #pragma unroll
    for (int j = 0; j < 4; ++j) {
      int R = R0 + (lane >> 4) * 4 + j;
      out[(size_t)R * IN + col] = acc[nq][j] + bb;
    }
  }
}

extern "C" void kernel_launch(void* const* d_in, const int* in_sizes, int n_in,
                              void* d_out, int out_size, void* d_ws, size_t ws_size,
                              hipStream_t stream) {
  const float* input_batch = (const float*)d_in[0];
  // d_in[1] target_batch: unused (no teacher forcing)
  const float* eWih = (const float*)d_in[2];
  const float* eWhh = (const float*)d_in[3];
  const float* ebih = (const float*)d_in[4];
  const float* ebhh = (const float*)d_in[5];
  const float* dWih = (const float*)d_in[6];
  const float* dWhh = (const float*)d_in[7];
  const float* dbih = (const float*)d_in[8];
  const float* dbhh = (const float*)d_in[9];
  const float* linW = (const float*)d_in[10];
  const float* linb = (const float*)d_in[11];
  float* out = (float*)d_out;

  char* ws = (char*)d_ws;
  size_t off = 0;
  auto alloc = [&](size_t bytes) -> void* {
    void* pp = ws + off;
    off = (off + bytes + 255) & ~(size_t)255;
    return pp;
  };
  unsigned short* xin   = (unsigned short*)alloc((size_t)SEQ * BATCH * IN * 2);
  unsigned short* Wenc  = (unsigned short*)alloc((size_t)G4 * KCAT * 2);
  float*          benc  = (float*)         alloc((size_t)G4 * 4);
  unsigned short* Wdec0 = (unsigned short*)alloc((size_t)G4 * KCAT * 2);
  float*          bdec0 = (float*)         alloc((size_t)G4 * 4);
  unsigned short* Wdeff = (unsigned short*)alloc((size_t)G4 * H * 2);
  float*          bdeff = (float*)         alloc((size_t)G4 * 4);
  unsigned short* linbf = (unsigned short*)alloc((size_t)IN * H * 2);
  unsigned short* hbuf  = (unsigned short*)alloc((size_t)2 * BATCH * H * 2);
  unsigned short* hhist = (unsigned short*)alloc((size_t)TLEN * BATCH * H * 2);
  unsigned int*   flags = (unsigned int*)  alloc((size_t)8 * 32 * sizeof(unsigned));
  unsigned int*   tickets = (unsigned int*)alloc((size_t)8 * sizeof(unsigned));
  (void)ws_size; (void)in_sizes; (void)n_in; (void)out_size;

  hipMemsetAsync(flags, 0, (size_t)8 * 32 * sizeof(unsigned), stream);
  hipMemsetAsync(tickets, 0, (size_t)8 * sizeof(unsigned), stream);
  hipLaunchKernelGGL(k_convert, dim3(512), dim3(256), 0, stream, input_batch, xin, SEQ * BATCH * IN);
  hipLaunchKernelGGL(k_convert, dim3(64),  dim3(256), 0, stream, linW, linbf, IN * H);
  hipLaunchKernelGGL(k_pack,   dim3(G4), dim3(256), 0, stream, eWih, eWhh, ebih, ebhh, Wenc, benc);
  hipLaunchKernelGGL(k_pack,   dim3(G4), dim3(256), 0, stream, dWih, dWhh, dbih, dbhh, Wdec0, bdec0);
  hipLaunchKernelGGL(k_deceff, dim3(G4), dim3(256), 0, stream, dWih, dWhh, dbih, dbhh, linW, linb, Wdeff, bdeff);

  void* args[] = { &xin, &Wenc, &benc, &Wdec0, &bdec0, &Wdeff, &bdeff, &hbuf, &hhist, &flags, &tickets };
  hipLaunchCooperativeKernel((void*)k_lstm, dim3(NBLK), dim3(512), args, 86016, stream);

  hipLaunchKernelGGL(k_out, dim3((TLEN * BATCH) / 64), dim3(256), 0, stream, hhist, linbf, linb, out);
}